// Round 3
// baseline (478.616 us; speedup 1.0000x reference)
//
#include <hip/hip_runtime.h>
#include <hip/hip_bf16.h>

// CavAttention: B=2, L=5, H=100, W=176, C=256, HEADS=8, DH=32, inner=256
#define LQ 5
#define HQ 100
#define WQ 176
#define HWQ 17600
#define NT 35200        // total (b,h,w) tiles = 2*HWQ
#define TPB 6           // tiles per block
#define ROWS 30         // TPB*LQ
#define NBLK 5867       // ceil(NT/TPB), last block has 4 tiles
#define SCALE_QK 0.17677669529663687f

// LDS layout (bytes):
//  AO    [30][512] bf16, XOR-swizzled : 0 .. 15360
//        (A-tile for GEMM1; overwritten by O after barrier; fragment reads of
//         rows 30/31 spill into qbuf region -> garbage, results discarded)
//  qbuf  4 waves x [30][192] bf16 swz : 15360 + wave*5760 .. 38400
//  gofs  [32] int                     : 38400
//  maskv [32] float                   : 38528
//  epilogue overlays [30][1024] f32 at 0..30720 (after barrier)
#define AO_OFF 0
#define QBUF_OFF 15360
#define QBUF_STRIDE 5760
#define GOFS_OFF 38400
#define MASK_OFF 38528
#define SMEM_BYTES 38656

typedef __attribute__((ext_vector_type(8))) short bf16x8;
typedef __attribute__((ext_vector_type(4))) float f32x4;
typedef __attribute__((ext_vector_type(2))) float f32x2;

__device__ __forceinline__ unsigned short f2bf(float f) {
  __hip_bfloat16 b = __float2bfloat16(f);
  return *(unsigned short*)&b;
}
__device__ __forceinline__ f32x2 bfpair(unsigned w) {
  union { unsigned u; float f; } lo, hi;
  lo.u = w << 16; hi.u = w & 0xffff0000u;
  return (f32x2){lo.f, hi.f};
}
__device__ __forceinline__ unsigned pack2(f32x2 v) {
  return ((unsigned)f2bf(v.y) << 16) | (unsigned)f2bf(v.x);
}
// swizzles: XOR bits 4-6 with row&7 (bijective; read/write use same map)
__device__ __forceinline__ int swzA(int row, int b) { return (row * 512 + b) ^ ((row & 7) << 4); }
__device__ __forceinline__ int swzQ(int row, int b) { return (row * 192 + b) ^ ((row & 7) << 4); }

// ---- prologue: W_qkv (256x768) -> WqkvT (768x256) bf16; W_out -> WoutT bf16
__global__ void prep_weights(const float* __restrict__ Wqkv,
                             const float* __restrict__ Wout,
                             unsigned short* __restrict__ WqkvT,
                             unsigned short* __restrict__ WoutT) {
  int idx = blockIdx.x * 256 + threadIdx.x;
  if (idx < 256 * 768) {
    int k = idx / 768, n = idx - k * 768;
    WqkvT[n * 256 + k] = f2bf(Wqkv[idx]);
  }
  if (idx < 256 * 256) {
    int k = idx >> 8, n = idx & 255;
    WoutT[n * 256 + k] = f2bf(Wout[idx]);
  }
}

// one head: GEMM1 slice (30x96) -> qbuf -> attention -> packed O in regs
__device__ __forceinline__ void do_head(int head, char* AO, char* qb,
                                        const unsigned short* __restrict__ WqkvT,
                                        const float* maskv,
                                        int lr, int lg, int lane,
                                        unsigned* oPk /*[8], static-indexed*/) {
  f32x4 acc[6][2];
  #pragma unroll
  for (int j = 0; j < 6; ++j) {
    acc[j][0] = (f32x4){0.f, 0.f, 0.f, 0.f};
    acc[j][1] = (f32x4){0.f, 0.f, 0.f, 0.f};
  }
  const int hb = head * 32;
  const int nb[6] = { hb, hb + 16, 256 + hb, 256 + hb + 16, 512 + hb, 512 + hb + 16 };

  #pragma unroll
  for (int kt = 0; kt < 8; ++kt) {
    bf16x8 a0 = *(const bf16x8*)(AO + swzA(lr,      kt * 64 + lg * 16));
    bf16x8 a1 = *(const bf16x8*)(AO + swzA(16 + lr, kt * 64 + lg * 16));  // rows 30/31 garbage, discarded
    #pragma unroll
    for (int j = 0; j < 6; ++j) {
      bf16x8 b = *(const bf16x8*)(WqkvT + (nb[j] + lr) * 256 + kt * 32 + lg * 8);
      acc[j][0] = __builtin_amdgcn_mfma_f32_16x16x32_bf16(a0, b, acc[j][0], 0, 0, 0);
      acc[j][1] = __builtin_amdgcn_mfma_f32_16x16x32_bf16(a1, b, acc[j][1], 0, 0, 0);
    }
  }

  // stash qkv into wave-private qbuf [30][96] bf16 swizzled
  #pragma unroll
  for (int j = 0; j < 6; ++j)
    #pragma unroll
    for (int mt = 0; mt < 2; ++mt)
      #pragma unroll
      for (int rg = 0; rg < 4; ++rg) {
        int row = mt * 16 + lg * 4 + rg;
        if (row < ROWS)
          *(unsigned short*)(qb + swzQ(row, (j * 16 + lr) * 2)) = f2bf(acc[j][mt][rg]);
      }

  // attention: lane = 2*row + half, 60 lanes active
  if (lane < 60) {
    const int r = lane >> 1, h = lane & 1;
    const int t5 = (r / 5) * 5;
    uint4 qa = *(const uint4*)(qb + swzQ(r, h * 32));
    uint4 qc = *(const uint4*)(qb + swzQ(r, h * 32 + 16));
    f32x2 q2[8];
    q2[0] = bfpair(qa.x); q2[1] = bfpair(qa.y); q2[2] = bfpair(qa.z); q2[3] = bfpair(qa.w);
    q2[4] = bfpair(qc.x); q2[5] = bfpair(qc.y); q2[6] = bfpair(qc.z); q2[7] = bfpair(qc.w);

    float p[5];
    #pragma unroll
    for (int j = 0; j < 5; ++j) {
      const int rk = t5 + j;
      uint4 ka = *(const uint4*)(qb + swzQ(rk, 64 + h * 32));
      uint4 kc = *(const uint4*)(qb + swzQ(rk, 64 + h * 32 + 16));
      f32x2 d2 = (f32x2){0.f, 0.f};
      d2 += q2[0] * bfpair(ka.x); d2 += q2[1] * bfpair(ka.y);
      d2 += q2[2] * bfpair(ka.z); d2 += q2[3] * bfpair(ka.w);
      d2 += q2[4] * bfpair(kc.x); d2 += q2[5] * bfpair(kc.y);
      d2 += q2[6] * bfpair(kc.z); d2 += q2[7] * bfpair(kc.w);
      float d = d2.x + d2.y;
      d += __shfl_xor(d, 1);
      p[j] = (maskv[rk] == 0.0f) ? -1e30f : d * SCALE_QK;
    }
    float mx = fmaxf(fmaxf(fmaxf(p[0], p[1]), fmaxf(p[2], p[3])), p[4]);
    float sum = 0.f;
    #pragma unroll
    for (int j = 0; j < 5; ++j) { p[j] = __expf(p[j] - mx); sum += p[j]; }
    const float inv = 1.0f / sum;

    f32x2 o2[8];
    #pragma unroll
    for (int c = 0; c < 8; ++c) o2[c] = (f32x2){0.f, 0.f};
    #pragma unroll
    for (int j = 0; j < 5; ++j) {
      const int rv = t5 + j;
      uint4 va = *(const uint4*)(qb + swzQ(rv, 128 + h * 32));
      uint4 vc = *(const uint4*)(qb + swzQ(rv, 128 + h * 32 + 16));
      f32x2 pj2 = (f32x2){p[j], p[j]};
      o2[0] += pj2 * bfpair(va.x); o2[1] += pj2 * bfpair(va.y);
      o2[2] += pj2 * bfpair(va.z); o2[3] += pj2 * bfpair(va.w);
      o2[4] += pj2 * bfpair(vc.x); o2[5] += pj2 * bfpair(vc.y);
      o2[6] += pj2 * bfpair(vc.z); o2[7] += pj2 * bfpair(vc.w);
    }
    f32x2 inv2 = (f32x2){inv, inv};
    #pragma unroll
    for (int c = 0; c < 8; ++c) oPk[c] = pack2(o2[c] * inv2);
  }
}

__global__ __launch_bounds__(256, 4)
void cav_attn_fused(const float* __restrict__ x,
                    const float* __restrict__ mask,
                    const unsigned short* __restrict__ WqkvT,
                    const unsigned short* __restrict__ WoutT,
                    const float* __restrict__ b_out,
                    float* __restrict__ out) {
  extern __shared__ char smem[];
  char*  AO    = smem + AO_OFF;
  int*   gofs  = (int*)(smem + GOFS_OFF);
  float* maskv = (float*)(smem + MASK_OFF);

  const int tid  = threadIdx.x;
  const int wave = tid >> 6;
  const int lane = tid & 63;
  const int lr   = lane & 15;
  const int lg   = lane >> 4;
  const int tile0 = blockIdx.x * TPB;
  const int nvalid = (NT - tile0 >= TPB) ? ROWS : (NT - tile0) * LQ;

  if (tid < ROWS) {
    int tt = tid / LQ;
    int l  = tid - tt * LQ;
    int gt = tile0 + tt;
    if (gt < NT) {
      int b = gt / HWQ;
      int rem = gt - b * HWQ;
      int h = rem / WQ;
      int w = rem - h * WQ;
      gofs[tid]  = (((b * LQ + l) * HQ + h) * WQ + w) << 8;
      maskv[tid] = mask[((b * HQ + h) * WQ + w) * LQ + l];
    } else {
      gofs[tid] = 0;
      maskv[tid] = 1.0f;
    }
  }
  __syncthreads();

  // ---- P0: stage x tile -> AO (bf16, swizzled)
  #pragma unroll
  for (int i = 0; i < 8; ++i) {
    int r = i * 4 + wave;
    if (r < ROWS) {
      f32x4 v = *(const f32x4*)(x + gofs[r] + lane * 4);
      ushort4 pk;
      pk.x = f2bf(v[0]); pk.y = f2bf(v[1]); pk.z = f2bf(v[2]); pk.w = f2bf(v[3]);
      *(ushort4*)(AO + swzA(r, lane * 8)) = pk;
    }
  }
  __syncthreads();

  char* qb = smem + QBUF_OFF + wave * QBUF_STRIDE;
  unsigned oPk0[8], oPk1[8];
  do_head(wave * 2,     AO, qb, WqkvT, maskv, lr, lg, lane, oPk0);
  do_head(wave * 2 + 1, AO, qb, WqkvT, maskv, lr, lg, lane, oPk1);

  __syncthreads();   // all GEMM1 A-reads complete across waves

  // ---- write O over the A region (bf16, swizzled)
  if (lane < 60) {
    const int r = lane >> 1, h = lane & 1;
    int b0 = (wave * 2) * 64 + h * 32;
    *(uint4*)(AO + swzA(r, b0))      = make_uint4(oPk0[0], oPk0[1], oPk0[2], oPk0[3]);
    *(uint4*)(AO + swzA(r, b0 + 16)) = make_uint4(oPk0[4], oPk0[5], oPk0[6], oPk0[7]);
    int b1 = (wave * 2 + 1) * 64 + h * 32;
    *(uint4*)(AO + swzA(r, b1))      = make_uint4(oPk1[0], oPk1[1], oPk1[2], oPk1[3]);
    *(uint4*)(AO + swzA(r, b1 + 16)) = make_uint4(oPk1[4], oPk1[5], oPk1[6], oPk1[7]);
  }
  __syncthreads();

  // ---- P2: out = O @ Wout + b_out; wave owns cols [wave*64, wave*64+64)
  f32x4 acc2[4][2];
  #pragma unroll
  for (int j = 0; j < 4; ++j) {
    acc2[j][0] = (f32x4){0.f, 0.f, 0.f, 0.f};
    acc2[j][1] = (f32x4){0.f, 0.f, 0.f, 0.f};
  }
  #pragma unroll
  for (int kt = 0; kt < 8; ++kt) {
    bf16x8 a0 = *(const bf16x8*)(AO + swzA(lr,      kt * 64 + lg * 16));
    bf16x8 a1 = *(const bf16x8*)(AO + swzA(16 + lr, kt * 64 + lg * 16));
    #pragma unroll
    for (int j = 0; j < 4; ++j) {
      bf16x8 b = *(const bf16x8*)(WoutT + (wave * 64 + j * 16 + lr) * 256 + kt * 32 + lg * 8);
      acc2[j][0] = __builtin_amdgcn_mfma_f32_16x16x32_bf16(a0, b, acc2[j][0], 0, 0, 0);
      acc2[j][1] = __builtin_amdgcn_mfma_f32_16x16x32_bf16(a1, b, acc2[j][1], 0, 0, 0);
    }
  }
  __syncthreads();   // O reads done before f32 overlay

  // ---- epilogue: stage f32 rows, then coalesced 1KB-row stores
  #pragma unroll
  for (int j = 0; j < 4; ++j) {
    const int col = wave * 64 + j * 16 + lr;
    const float bo = b_out[col];
    #pragma unroll
    for (int mt = 0; mt < 2; ++mt)
      #pragma unroll
      for (int rg = 0; rg < 4; ++rg) {
        int row = mt * 16 + lg * 4 + rg;
        if (row < ROWS)
          *(float*)(smem + row * 1024 + col * 4) = acc2[j][mt][rg] + bo;
      }
  }
  __syncthreads();
  #pragma unroll
  for (int i = 0; i < 8; ++i) {
    int r = i * 4 + wave;
    if (r < nvalid) {
      f32x4 v = *(const f32x4*)(smem + r * 1024 + lane * 16);
      *(f32x4*)(out + gofs[r] + lane * 4) = v;
    }
  }
}

extern "C" void kernel_launch(void* const* d_in, const int* in_sizes, int n_in,
                              void* d_out, int out_size, void* d_ws, size_t ws_size,
                              hipStream_t stream) {
  (void)in_sizes; (void)n_in; (void)out_size; (void)ws_size;
  const float* x    = (const float*)d_in[0];
  const float* mask = (const float*)d_in[1];
  const float* Wqkv = (const float*)d_in[2];
  const float* Wout = (const float*)d_in[3];
  const float* bout = (const float*)d_in[4];
  float* out = (float*)d_out;

  unsigned short* WqkvT = (unsigned short*)d_ws;        // [768][256]
  unsigned short* WoutT = WqkvT + 768 * 256;            // [256][256]

  (void)hipFuncSetAttribute((const void*)cav_attn_fused,
                            hipFuncAttributeMaxDynamicSharedMemorySize, SMEM_BYTES);

  prep_weights<<<768, 256, 0, stream>>>(Wqkv, Wout, WqkvT, WoutT);
  cav_attn_fused<<<NBLK, 256, SMEM_BYTES, stream>>>(x, mask, WqkvT, WoutT, bout, out);
}

// Round 4
// 457.927 us; speedup vs baseline: 1.0452x; 1.0452x over previous
//
#include <hip/hip_runtime.h>
#include <hip/hip_bf16.h>

// CavAttention: B=2, L=5, H=100, W=176, C=256, HEADS=8, DH=32, inner=256
#define LQ 5
#define HQ 100
#define WQ 176
#define HWQ 17600
#define NT 35200        // total (b,h,w) tiles = 2*HWQ
#define TPB 6           // tiles per block
#define ROWS 30         // TPB*LQ
#define NBLK 5867       // ceil(NT/TPB), last block has 4 tiles
#define SCALE_QK 0.17677669529663687f

// LDS layout (bytes):
//  AO    [30][512] bf16, XOR-swizzled : 0 .. 15360
//        (A-tile for GEMM1; overwritten by O after barrier; fragment reads of
//         rows 30/31 spill into qbuf region -> garbage, results discarded)
//  qbuf  4 waves x [30][192] bf16 swz : 15360 + wave*5760 .. 38400
//  gofs  [32] int                     : 38400
//  maskv [32] float                   : 38528
#define AO_OFF 0
#define QBUF_OFF 15360
#define QBUF_STRIDE 5760
#define GOFS_OFF 38400
#define MASK_OFF 38528
#define SMEM_BYTES 38656

typedef __attribute__((ext_vector_type(8))) short bf16x8;
typedef __attribute__((ext_vector_type(4))) float f32x4;
typedef __attribute__((ext_vector_type(2))) float f32x2;

__device__ __forceinline__ unsigned short f2bf(float f) {
  __hip_bfloat16 b = __float2bfloat16(f);
  return *(unsigned short*)&b;
}
__device__ __forceinline__ f32x2 bfpair(unsigned w) {
  union { unsigned u; float f; } lo, hi;
  lo.u = w << 16; hi.u = w & 0xffff0000u;
  return (f32x2){lo.f, hi.f};
}
__device__ __forceinline__ unsigned pack2(f32x2 v) {
  return ((unsigned)f2bf(v.y) << 16) | (unsigned)f2bf(v.x);
}
// swizzles: XOR bits 4-6 with row&7 (bijective; read/write use same map)
__device__ __forceinline__ int swzA(int row, int b) { return (row * 512 + b) ^ ((row & 7) << 4); }
__device__ __forceinline__ int swzQ(int row, int b) { return (row * 192 + b) ^ ((row & 7) << 4); }

// ---- prologue: W_qkv (256x768) -> WqkvT (768x256) bf16; W_out -> WoutT bf16
__global__ void prep_weights(const float* __restrict__ Wqkv,
                             const float* __restrict__ Wout,
                             unsigned short* __restrict__ WqkvT,
                             unsigned short* __restrict__ WoutT) {
  int idx = blockIdx.x * 256 + threadIdx.x;
  if (idx < 256 * 768) {
    int k = idx / 768, n = idx - k * 768;
    WqkvT[n * 256 + k] = f2bf(Wqkv[idx]);
  }
  if (idx < 256 * 256) {
    int k = idx >> 8, n = idx & 255;
    WoutT[n * 256 + k] = f2bf(Wout[idx]);
  }
}

// one head: GEMM1 in two register-light groups -> qbuf -> attention -> packed O regs
__device__ __forceinline__ void do_head(int head, char* AO, char* qb,
                                        const unsigned short* __restrict__ WqkvT,
                                        const float* maskv,
                                        int lr, int lg, int lane,
                                        unsigned* oPk /*[8], static-indexed*/) {
  const int hb = head * 32;

  // ---- group 0: q,k (acc = 32 regs)
  {
    f32x4 acc[4][2];
    #pragma unroll
    for (int j = 0; j < 4; ++j) {
      acc[j][0] = (f32x4){0.f, 0.f, 0.f, 0.f};
      acc[j][1] = (f32x4){0.f, 0.f, 0.f, 0.f};
    }
    const int nb[4] = { hb, hb + 16, 256 + hb, 256 + hb + 16 };
    #pragma unroll
    for (int kt = 0; kt < 8; ++kt) {
      bf16x8 a0 = *(const bf16x8*)(AO + swzA(lr,      kt * 64 + lg * 16));
      bf16x8 a1 = *(const bf16x8*)(AO + swzA(16 + lr, kt * 64 + lg * 16)); // rows 30/31 garbage, discarded
      #pragma unroll
      for (int j = 0; j < 4; ++j) {
        bf16x8 b = *(const bf16x8*)(WqkvT + (nb[j] + lr) * 256 + kt * 32 + lg * 8);
        acc[j][0] = __builtin_amdgcn_mfma_f32_16x16x32_bf16(a0, b, acc[j][0], 0, 0, 0);
        acc[j][1] = __builtin_amdgcn_mfma_f32_16x16x32_bf16(a1, b, acc[j][1], 0, 0, 0);
      }
    }
    #pragma unroll
    for (int j = 0; j < 4; ++j)
      #pragma unroll
      for (int mt = 0; mt < 2; ++mt)
        #pragma unroll
        for (int rg = 0; rg < 4; ++rg) {
          int row = mt * 16 + lg * 4 + rg;
          if (row < ROWS)
            *(unsigned short*)(qb + swzQ(row, (j * 16 + lr) * 2)) = f2bf(acc[j][mt][rg]);
        }
  }

  // ---- group 1: v (acc = 16 regs)
  {
    f32x4 acc[2][2];
    #pragma unroll
    for (int j = 0; j < 2; ++j) {
      acc[j][0] = (f32x4){0.f, 0.f, 0.f, 0.f};
      acc[j][1] = (f32x4){0.f, 0.f, 0.f, 0.f};
    }
    const int nb[2] = { 512 + hb, 512 + hb + 16 };
    #pragma unroll
    for (int kt = 0; kt < 8; ++kt) {
      bf16x8 a0 = *(const bf16x8*)(AO + swzA(lr,      kt * 64 + lg * 16));
      bf16x8 a1 = *(const bf16x8*)(AO + swzA(16 + lr, kt * 64 + lg * 16));
      #pragma unroll
      for (int j = 0; j < 2; ++j) {
        bf16x8 b = *(const bf16x8*)(WqkvT + (nb[j] + lr) * 256 + kt * 32 + lg * 8);
        acc[j][0] = __builtin_amdgcn_mfma_f32_16x16x32_bf16(a0, b, acc[j][0], 0, 0, 0);
        acc[j][1] = __builtin_amdgcn_mfma_f32_16x16x32_bf16(a1, b, acc[j][1], 0, 0, 0);
      }
    }
    #pragma unroll
    for (int j = 0; j < 2; ++j)
      #pragma unroll
      for (int mt = 0; mt < 2; ++mt)
        #pragma unroll
        for (int rg = 0; rg < 4; ++rg) {
          int row = mt * 16 + lg * 4 + rg;
          if (row < ROWS)
            *(unsigned short*)(qb + swzQ(row, (64 + j * 16 + lr) * 2)) = f2bf(acc[j][mt][rg]);
        }
  }

  // ---- attention: lane = 2*row + half, 60 lanes active
  if (lane < 60) {
    const int r = lane >> 1, h = lane & 1;
    const int t5 = (r / 5) * 5;
    uint4 qa = *(const uint4*)(qb + swzQ(r, h * 32));
    uint4 qc = *(const uint4*)(qb + swzQ(r, h * 32 + 16));
    f32x2 q2[8];
    q2[0] = bfpair(qa.x); q2[1] = bfpair(qa.y); q2[2] = bfpair(qa.z); q2[3] = bfpair(qa.w);
    q2[4] = bfpair(qc.x); q2[5] = bfpair(qc.y); q2[6] = bfpair(qc.z); q2[7] = bfpair(qc.w);

    float p[5];
    #pragma unroll
    for (int j = 0; j < 5; ++j) {
      const int rk = t5 + j;
      uint4 ka = *(const uint4*)(qb + swzQ(rk, 64 + h * 32));
      uint4 kc = *(const uint4*)(qb + swzQ(rk, 64 + h * 32 + 16));
      f32x2 d2 = (f32x2){0.f, 0.f};
      d2 += q2[0] * bfpair(ka.x); d2 += q2[1] * bfpair(ka.y);
      d2 += q2[2] * bfpair(ka.z); d2 += q2[3] * bfpair(ka.w);
      d2 += q2[4] * bfpair(kc.x); d2 += q2[5] * bfpair(kc.y);
      d2 += q2[6] * bfpair(kc.z); d2 += q2[7] * bfpair(kc.w);
      float d = d2.x + d2.y;
      d += __shfl_xor(d, 1);
      p[j] = (maskv[rk] == 0.0f) ? -1e30f : d * SCALE_QK;
    }
    float mx = fmaxf(fmaxf(fmaxf(p[0], p[1]), fmaxf(p[2], p[3])), p[4]);
    float sum = 0.f;
    #pragma unroll
    for (int j = 0; j < 5; ++j) { p[j] = __expf(p[j] - mx); sum += p[j]; }
    const float inv = 1.0f / sum;

    f32x2 o2[8];
    #pragma unroll
    for (int c = 0; c < 8; ++c) o2[c] = (f32x2){0.f, 0.f};
    #pragma unroll
    for (int j = 0; j < 5; ++j) {
      const int rv = t5 + j;
      uint4 va = *(const uint4*)(qb + swzQ(rv, 128 + h * 32));
      uint4 vc = *(const uint4*)(qb + swzQ(rv, 128 + h * 32 + 16));
      f32x2 pj2 = (f32x2){p[j], p[j]};
      o2[0] += pj2 * bfpair(va.x); o2[1] += pj2 * bfpair(va.y);
      o2[2] += pj2 * bfpair(va.z); o2[3] += pj2 * bfpair(va.w);
      o2[4] += pj2 * bfpair(vc.x); o2[5] += pj2 * bfpair(vc.y);
      o2[6] += pj2 * bfpair(vc.z); o2[7] += pj2 * bfpair(vc.w);
    }
    f32x2 inv2 = (f32x2){inv, inv};
    #pragma unroll
    for (int c = 0; c < 8; ++c) oPk[c] = pack2(o2[c] * inv2);
  }
}

__global__ __launch_bounds__(256, 4)
void cav_attn_fused(const float* __restrict__ x,
                    const float* __restrict__ mask,
                    const unsigned short* __restrict__ WqkvT,
                    const unsigned short* __restrict__ WoutT,
                    const float* __restrict__ b_out,
                    float* __restrict__ out) {
  extern __shared__ char smem[];
  char*  AO    = smem + AO_OFF;
  int*   gofs  = (int*)(smem + GOFS_OFF);
  float* maskv = (float*)(smem + MASK_OFF);

  const int tid  = threadIdx.x;
  const int wave = tid >> 6;
  const int lane = tid & 63;
  const int lr   = lane & 15;
  const int lg   = lane >> 4;
  const int tile0 = blockIdx.x * TPB;
  const int nvalid = (NT - tile0 >= TPB) ? ROWS : (NT - tile0) * LQ;

  if (tid < ROWS) {
    int tt = tid / LQ;
    int l  = tid - tt * LQ;
    int gt = tile0 + tt;
    if (gt < NT) {
      int b = gt / HWQ;
      int rem = gt - b * HWQ;
      int h = rem / WQ;
      int w = rem - h * WQ;
      gofs[tid]  = (((b * LQ + l) * HQ + h) * WQ + w) << 8;
      maskv[tid] = mask[((b * HQ + h) * WQ + w) * LQ + l];
    } else {
      gofs[tid] = 0;
      maskv[tid] = 1.0f;
    }
  }
  __syncthreads();

  // ---- P0: stage x tile -> AO (bf16, swizzled)
  #pragma unroll
  for (int i = 0; i < 8; ++i) {
    int r = i * 4 + wave;
    if (r < ROWS) {
      f32x4 v = *(const f32x4*)(x + gofs[r] + lane * 4);
      ushort4 pk;
      pk.x = f2bf(v[0]); pk.y = f2bf(v[1]); pk.z = f2bf(v[2]); pk.w = f2bf(v[3]);
      *(ushort4*)(AO + swzA(r, lane * 8)) = pk;
    }
  }
  __syncthreads();

  char* qb = smem + QBUF_OFF + wave * QBUF_STRIDE;
  unsigned oPk0[8], oPk1[8];
  do_head(wave * 2,     AO, qb, WqkvT, maskv, lr, lg, lane, oPk0);
  do_head(wave * 2 + 1, AO, qb, WqkvT, maskv, lr, lg, lane, oPk1);

  __syncthreads();   // all GEMM1 A-reads complete across waves

  // ---- write O over the A region (bf16, swizzled)
  if (lane < 60) {
    const int r = lane >> 1, h = lane & 1;
    int b0 = (wave * 2) * 64 + h * 32;
    *(uint4*)(AO + swzA(r, b0))      = make_uint4(oPk0[0], oPk0[1], oPk0[2], oPk0[3]);
    *(uint4*)(AO + swzA(r, b0 + 16)) = make_uint4(oPk0[4], oPk0[5], oPk0[6], oPk0[7]);
    int b1 = (wave * 2 + 1) * 64 + h * 32;
    *(uint4*)(AO + swzA(r, b1))      = make_uint4(oPk1[0], oPk1[1], oPk1[2], oPk1[3]);
    *(uint4*)(AO + swzA(r, b1 + 16)) = make_uint4(oPk1[4], oPk1[5], oPk1[6], oPk1[7]);
  }
  __syncthreads();

  // ---- P2: out = O @ Wout + b_out; wave owns cols [wave*64, wave*64+64)
  f32x4 acc2[4][2];
  #pragma unroll
  for (int j = 0; j < 4; ++j) {
    acc2[j][0] = (f32x4){0.f, 0.f, 0.f, 0.f};
    acc2[j][1] = (f32x4){0.f, 0.f, 0.f, 0.f};
  }
  #pragma unroll
  for (int kt = 0; kt < 8; ++kt) {
    bf16x8 a0 = *(const bf16x8*)(AO + swzA(lr,      kt * 64 + lg * 16));
    bf16x8 a1 = *(const bf16x8*)(AO + swzA(16 + lr, kt * 64 + lg * 16));
    #pragma unroll
    for (int j = 0; j < 4; ++j) {
      bf16x8 b = *(const bf16x8*)(WoutT + (wave * 64 + j * 16 + lr) * 256 + kt * 32 + lg * 8);
      acc2[j][0] = __builtin_amdgcn_mfma_f32_16x16x32_bf16(a0, b, acc2[j][0], 0, 0, 0);
      acc2[j][1] = __builtin_amdgcn_mfma_f32_16x16x32_bf16(a1, b, acc2[j][1], 0, 0, 0);
    }
  }

  // ---- direct global stores (64B-coalesced per 16-lane group), no LDS round trip
  #pragma unroll
  for (int j = 0; j < 4; ++j) {
    const int col = wave * 64 + j * 16 + lr;
    const float bo = b_out[col];
    #pragma unroll
    for (int mt = 0; mt < 2; ++mt)
      #pragma unroll
      for (int rg = 0; rg < 4; ++rg) {
        int row = mt * 16 + lg * 4 + rg;
        if (row < nvalid)
          out[gofs[row] + col] = acc2[j][mt][rg] + bo;
      }
  }
}

extern "C" void kernel_launch(void* const* d_in, const int* in_sizes, int n_in,
                              void* d_out, int out_size, void* d_ws, size_t ws_size,
                              hipStream_t stream) {
  (void)in_sizes; (void)n_in; (void)out_size; (void)ws_size;
  const float* x    = (const float*)d_in[0];
  const float* mask = (const float*)d_in[1];
  const float* Wqkv = (const float*)d_in[2];
  const float* Wout = (const float*)d_in[3];
  const float* bout = (const float*)d_in[4];
  float* out = (float*)d_out;

  unsigned short* WqkvT = (unsigned short*)d_ws;        // [768][256]
  unsigned short* WoutT = WqkvT + 768 * 256;            // [256][256]

  (void)hipFuncSetAttribute((const void*)cav_attn_fused,
                            hipFuncAttributeMaxDynamicSharedMemorySize, SMEM_BYTES);

  prep_weights<<<768, 256, 0, stream>>>(Wqkv, Wout, WqkvT, WoutT);
  cav_attn_fused<<<NBLK, 256, SMEM_BYTES, stream>>>(x, mask, WqkvT, WoutT, bout, out);
}

// Round 5
// 442.149 us; speedup vs baseline: 1.0825x; 1.0357x over previous
//
#include <hip/hip_runtime.h>
#include <hip/hip_bf16.h>

// CavAttention: B=2, L=5, H=100, W=176, C=256, HEADS=8, DH=32, inner=256
#define LQ 5
#define HQ 100
#define WQ 176
#define HWQ 17600
#define NT 35200        // total (b,h,w) tiles = 2*HWQ
#define TPB 6           // tiles per block
#define ROWS 30         // TPB*LQ
#define NBLK 5867       // ceil(NT/TPB), last block has 4 tiles
#define SCALE_QK 0.17677669529663687f

// LDS layout (bytes):
//  AO    [30][512] bf16, XOR-swizzled : 0 .. 15360
//        (A-tile for GEMM1; overwritten by O after barrier; fragment reads of
//         rows 30/31 spill into qbuf region -> garbage, results discarded)
//  qbuf  4 waves x [30][192] bf16 swz : 15360 + wave*5760 .. 38400
//  gofs  [32] int                     : 38400
//  maskv [32] float                   : 38528
#define AO_OFF 0
#define QBUF_OFF 15360
#define QBUF_STRIDE 5760
#define GOFS_OFF 38400
#define MASK_OFF 38528
#define SMEM_BYTES 38656

typedef __attribute__((ext_vector_type(8))) short bf16x8;
typedef __attribute__((ext_vector_type(4))) float f32x4;
typedef __attribute__((ext_vector_type(2))) float f32x2;

__device__ __forceinline__ unsigned short f2bf(float f) {
  __hip_bfloat16 b = __float2bfloat16(f);
  return *(unsigned short*)&b;
}
__device__ __forceinline__ f32x2 bfpair(unsigned w) {
  union { unsigned u; float f; } lo, hi;
  lo.u = w << 16; hi.u = w & 0xffff0000u;
  return (f32x2){lo.f, hi.f};
}
__device__ __forceinline__ unsigned pack2(f32x2 v) {
  return ((unsigned)f2bf(v.y) << 16) | (unsigned)f2bf(v.x);
}
// swizzles: XOR bits 4-6 with row&7 (bijective; read/write use same map)
__device__ __forceinline__ int swzA(int row, int b) { return (row * 512 + b) ^ ((row & 7) << 4); }
__device__ __forceinline__ int swzQ(int row, int b) { return (row * 192 + b) ^ ((row & 7) << 4); }

// ---- prologue: W_qkv (256x768) -> WqkvT (768x256) bf16; W_out -> WoutT bf16
__global__ void prep_weights(const float* __restrict__ Wqkv,
                             const float* __restrict__ Wout,
                             unsigned short* __restrict__ WqkvT,
                             unsigned short* __restrict__ WoutT) {
  int idx = blockIdx.x * 256 + threadIdx.x;
  if (idx < 256 * 768) {
    int k = idx / 768, n = idx - k * 768;
    WqkvT[n * 256 + k] = f2bf(Wqkv[idx]);
  }
  if (idx < 256 * 256) {
    int k = idx >> 8, n = idx & 255;
    WoutT[n * 256 + k] = f2bf(Wout[idx]);
  }
}

// one head: GEMM1 slice (30x96) -> qbuf -> attention -> packed O in regs
__device__ __forceinline__ void do_head(int head, char* AO, char* qb,
                                        const unsigned short* __restrict__ WqkvT,
                                        const float* maskv,
                                        int lr, int lg, int lane,
                                        unsigned* oPk /*[8], static-indexed*/) {
  f32x4 acc[6][2];
  #pragma unroll
  for (int j = 0; j < 6; ++j) {
    acc[j][0] = (f32x4){0.f, 0.f, 0.f, 0.f};
    acc[j][1] = (f32x4){0.f, 0.f, 0.f, 0.f};
  }
  const int hb = head * 32;
  const int nb[6] = { hb, hb + 16, 256 + hb, 256 + hb + 16, 512 + hb, 512 + hb + 16 };

  #pragma unroll
  for (int kt = 0; kt < 8; ++kt) {
    bf16x8 a0 = *(const bf16x8*)(AO + swzA(lr,      kt * 64 + lg * 16));
    bf16x8 a1 = *(const bf16x8*)(AO + swzA(16 + lr, kt * 64 + lg * 16));  // rows 30/31 garbage, discarded
    #pragma unroll
    for (int j = 0; j < 6; ++j) {
      bf16x8 b = *(const bf16x8*)(WqkvT + (nb[j] + lr) * 256 + kt * 32 + lg * 8);
      acc[j][0] = __builtin_amdgcn_mfma_f32_16x16x32_bf16(a0, b, acc[j][0], 0, 0, 0);
      acc[j][1] = __builtin_amdgcn_mfma_f32_16x16x32_bf16(a1, b, acc[j][1], 0, 0, 0);
    }
  }

  // stash qkv into wave-private qbuf [30][96] bf16 swizzled
  #pragma unroll
  for (int j = 0; j < 6; ++j)
    #pragma unroll
    for (int mt = 0; mt < 2; ++mt)
      #pragma unroll
      for (int rg = 0; rg < 4; ++rg) {
        int row = mt * 16 + lg * 4 + rg;
        if (row < ROWS)
          *(unsigned short*)(qb + swzQ(row, (j * 16 + lr) * 2)) = f2bf(acc[j][mt][rg]);
      }

  // attention: lane = 2*row + half, 60 lanes active
  if (lane < 60) {
    const int r = lane >> 1, h = lane & 1;
    const int t5 = (r / 5) * 5;
    uint4 qa = *(const uint4*)(qb + swzQ(r, h * 32));
    uint4 qc = *(const uint4*)(qb + swzQ(r, h * 32 + 16));
    f32x2 q2[8];
    q2[0] = bfpair(qa.x); q2[1] = bfpair(qa.y); q2[2] = bfpair(qa.z); q2[3] = bfpair(qa.w);
    q2[4] = bfpair(qc.x); q2[5] = bfpair(qc.y); q2[6] = bfpair(qc.z); q2[7] = bfpair(qc.w);

    float p[5];
    #pragma unroll
    for (int j = 0; j < 5; ++j) {
      const int rk = t5 + j;
      uint4 ka = *(const uint4*)(qb + swzQ(rk, 64 + h * 32));
      uint4 kc = *(const uint4*)(qb + swzQ(rk, 64 + h * 32 + 16));
      f32x2 d2 = (f32x2){0.f, 0.f};
      d2 += q2[0] * bfpair(ka.x); d2 += q2[1] * bfpair(ka.y);
      d2 += q2[2] * bfpair(ka.z); d2 += q2[3] * bfpair(ka.w);
      d2 += q2[4] * bfpair(kc.x); d2 += q2[5] * bfpair(kc.y);
      d2 += q2[6] * bfpair(kc.z); d2 += q2[7] * bfpair(kc.w);
      float d = d2.x + d2.y;
      d += __shfl_xor(d, 1);
      p[j] = (maskv[rk] == 0.0f) ? -1e30f : d * SCALE_QK;
    }
    float mx = fmaxf(fmaxf(fmaxf(p[0], p[1]), fmaxf(p[2], p[3])), p[4]);
    float sum = 0.f;
    #pragma unroll
    for (int j = 0; j < 5; ++j) { p[j] = __expf(p[j] - mx); sum += p[j]; }
    const float inv = 1.0f / sum;

    f32x2 o2[8];
    #pragma unroll
    for (int c = 0; c < 8; ++c) o2[c] = (f32x2){0.f, 0.f};
    #pragma unroll
    for (int j = 0; j < 5; ++j) {
      const int rv = t5 + j;
      uint4 va = *(const uint4*)(qb + swzQ(rv, 128 + h * 32));
      uint4 vc = *(const uint4*)(qb + swzQ(rv, 128 + h * 32 + 16));
      f32x2 pj2 = (f32x2){p[j], p[j]};
      o2[0] += pj2 * bfpair(va.x); o2[1] += pj2 * bfpair(va.y);
      o2[2] += pj2 * bfpair(va.z); o2[3] += pj2 * bfpair(va.w);
      o2[4] += pj2 * bfpair(vc.x); o2[5] += pj2 * bfpair(vc.y);
      o2[6] += pj2 * bfpair(vc.z); o2[7] += pj2 * bfpair(vc.w);
    }
    f32x2 inv2 = (f32x2){inv, inv};
    #pragma unroll
    for (int c = 0; c < 8; ++c) oPk[c] = pack2(o2[c] * inv2);
  }
}

__global__ __launch_bounds__(256, 3)
void cav_attn_fused(const float* __restrict__ x,
                    const float* __restrict__ mask,
                    const unsigned short* __restrict__ WqkvT,
                    const unsigned short* __restrict__ WoutT,
                    const float* __restrict__ b_out,
                    float* __restrict__ out) {
  extern __shared__ char smem[];
  char*  AO    = smem + AO_OFF;
  int*   gofs  = (int*)(smem + GOFS_OFF);
  float* maskv = (float*)(smem + MASK_OFF);

  const int tid  = threadIdx.x;
  const int wave = tid >> 6;
  const int lane = tid & 63;
  const int lr   = lane & 15;
  const int lg   = lane >> 4;
  const int tile0 = blockIdx.x * TPB;
  const int nvalid = (NT - tile0 >= TPB) ? ROWS : (NT - tile0) * LQ;

  if (tid < ROWS) {
    int tt = tid / LQ;
    int l  = tid - tt * LQ;
    int gt = tile0 + tt;
    if (gt < NT) {
      int b = gt / HWQ;
      int rem = gt - b * HWQ;
      int h = rem / WQ;
      int w = rem - h * WQ;
      gofs[tid]  = (((b * LQ + l) * HQ + h) * WQ + w) << 8;
      maskv[tid] = mask[((b * HQ + h) * WQ + w) * LQ + l];
    } else {
      gofs[tid] = 0;
      maskv[tid] = 1.0f;
    }
  }
  __syncthreads();

  // ---- P0: stage x tile -> AO (bf16, swizzled)
  #pragma unroll
  for (int i = 0; i < 8; ++i) {
    int r = i * 4 + wave;
    if (r < ROWS) {
      f32x4 v = *(const f32x4*)(x + gofs[r] + lane * 4);
      ushort4 pk;
      pk.x = f2bf(v[0]); pk.y = f2bf(v[1]); pk.z = f2bf(v[2]); pk.w = f2bf(v[3]);
      *(ushort4*)(AO + swzA(r, lane * 8)) = pk;
    }
  }
  __syncthreads();

  char* qb = smem + QBUF_OFF + wave * QBUF_STRIDE;
  unsigned oPk0[8], oPk1[8];
  do_head(wave * 2,     AO, qb, WqkvT, maskv, lr, lg, lane, oPk0);
  do_head(wave * 2 + 1, AO, qb, WqkvT, maskv, lr, lg, lane, oPk1);

  __syncthreads();   // all GEMM1 A-reads complete across waves

  // ---- write O over the A region (bf16, swizzled)
  if (lane < 60) {
    const int r = lane >> 1, h = lane & 1;
    int b0 = (wave * 2) * 64 + h * 32;
    *(uint4*)(AO + swzA(r, b0))      = make_uint4(oPk0[0], oPk0[1], oPk0[2], oPk0[3]);
    *(uint4*)(AO + swzA(r, b0 + 16)) = make_uint4(oPk0[4], oPk0[5], oPk0[6], oPk0[7]);
    int b1 = (wave * 2 + 1) * 64 + h * 32;
    *(uint4*)(AO + swzA(r, b1))      = make_uint4(oPk1[0], oPk1[1], oPk1[2], oPk1[3]);
    *(uint4*)(AO + swzA(r, b1 + 16)) = make_uint4(oPk1[4], oPk1[5], oPk1[6], oPk1[7]);
  }
  __syncthreads();

  // ---- P2: out = O @ Wout + b_out; wave owns cols [wave*64, wave*64+64)
  f32x4 acc2[4][2];
  #pragma unroll
  for (int j = 0; j < 4; ++j) {
    acc2[j][0] = (f32x4){0.f, 0.f, 0.f, 0.f};
    acc2[j][1] = (f32x4){0.f, 0.f, 0.f, 0.f};
  }
  #pragma unroll
  for (int kt = 0; kt < 8; ++kt) {
    bf16x8 a0 = *(const bf16x8*)(AO + swzA(lr,      kt * 64 + lg * 16));
    bf16x8 a1 = *(const bf16x8*)(AO + swzA(16 + lr, kt * 64 + lg * 16));
    #pragma unroll
    for (int j = 0; j < 4; ++j) {
      bf16x8 b = *(const bf16x8*)(WoutT + (wave * 64 + j * 16 + lr) * 256 + kt * 32 + lg * 8);
      acc2[j][0] = __builtin_amdgcn_mfma_f32_16x16x32_bf16(a0, b, acc2[j][0], 0, 0, 0);
      acc2[j][1] = __builtin_amdgcn_mfma_f32_16x16x32_bf16(a1, b, acc2[j][1], 0, 0, 0);
    }
  }

  // ---- direct global stores (64B-coalesced per 16-lane group), no LDS round trip
  #pragma unroll
  for (int j = 0; j < 4; ++j) {
    const int col = wave * 64 + j * 16 + lr;
    const float bo = b_out[col];
    #pragma unroll
    for (int mt = 0; mt < 2; ++mt)
      #pragma unroll
      for (int rg = 0; rg < 4; ++rg) {
        int row = mt * 16 + lg * 4 + rg;
        if (row < nvalid)
          out[gofs[row] + col] = acc2[j][mt][rg] + bo;
      }
  }
}

extern "C" void kernel_launch(void* const* d_in, const int* in_sizes, int n_in,
                              void* d_out, int out_size, void* d_ws, size_t ws_size,
                              hipStream_t stream) {
  (void)in_sizes; (void)n_in; (void)out_size; (void)ws_size;
  const float* x    = (const float*)d_in[0];
  const float* mask = (const float*)d_in[1];
  const float* Wqkv = (const float*)d_in[2];
  const float* Wout = (const float*)d_in[3];
  const float* bout = (const float*)d_in[4];
  float* out = (float*)d_out;

  unsigned short* WqkvT = (unsigned short*)d_ws;        // [768][256]
  unsigned short* WoutT = WqkvT + 768 * 256;            // [256][256]

  (void)hipFuncSetAttribute((const void*)cav_attn_fused,
                            hipFuncAttributeMaxDynamicSharedMemorySize, SMEM_BYTES);

  prep_weights<<<768, 256, 0, stream>>>(Wqkv, Wout, WqkvT, WoutT);
  cav_attn_fused<<<NBLK, 256, SMEM_BYTES, stream>>>(x, mask, WqkvT, WoutT, bout, out);
}

// Round 6
// 382.493 us; speedup vs baseline: 1.2513x; 1.1560x over previous
//
#include <hip/hip_runtime.h>
#include <hip/hip_bf16.h>

// CavAttention: B=2, L=5, H=100, W=176, C=256, HEADS=8, DH=32, inner=256
#define LQ 5
#define HQ 100
#define WQ 176
#define HWQ 17600
#define NT 35200        // total (b,h,w) tiles = 2*HWQ
#define TPB 8           // tiles per block
#define ROWS 40         // TPB*LQ
#define NBLK 4400       // NT/TPB exact, no tail
#define SCALE_QK 0.17677669529663687f

// LDS layout (bytes):
//  AO    [40][512B] bf16 XOR-swizzled : 0     .. 20480
//        (A-tile for GEMM1; O overwrites it after a barrier; m-tile-2 fragment
//         reads of rows 40..47 spill into qbuf region -> garbage, discarded)
//  qbuf  4 waves x [40][192B] bf16 swz: 20480 .. 51200   (wave stride 7680)
//  epilogue overlays f32 [40][1024B] at 0..40960 (after barrier, qbuf dead)
#define AO_OFF 0
#define QBUF_OFF 20480
#define QBUF_STRIDE 7680
#define SMEM_BYTES 51200

typedef __attribute__((ext_vector_type(8))) short bf16x8;
typedef __attribute__((ext_vector_type(4))) float f32x4;
typedef __attribute__((ext_vector_type(2))) float f32x2;

__device__ __forceinline__ unsigned short f2bf(float f) {
  __hip_bfloat16 b = __float2bfloat16(f);
  return *(unsigned short*)&b;
}
__device__ __forceinline__ f32x2 bfpair(unsigned w) {
  union { unsigned u; float f; } lo, hi;
  lo.u = w << 16; hi.u = w & 0xffff0000u;
  return (f32x2){lo.f, hi.f};
}
__device__ __forceinline__ unsigned pack2(f32x2 v) {
  return ((unsigned)f2bf(v.y) << 16) | (unsigned)f2bf(v.x);
}
// XOR bits 4-6 of the linear address with row&7. Bijective for both strides
// (512 = 4x128 aligned; 192-stride splits are half-128-block aligned).
__device__ __forceinline__ int swzA(int row, int b) { return (row * 512 + b) ^ ((row & 7) << 4); }
__device__ __forceinline__ int swzQ(int row, int b) { return (row * 192 + b) ^ ((row & 7) << 4); }

// row r of this block -> global float offset of its 256-float x/out row
__device__ __forceinline__ int row_gofs(int tile0, int r) {
  int gt = tile0 + r / 5;
  int l  = r - (r / 5) * 5;
  int b  = (gt >= HWQ) ? 1 : 0;
  int rem = gt - b * HWQ;          // h*WQ + w
  return (((b * LQ + l) * HQ) * WQ + rem) << 8;   // ((b*L+l)*HQ+h)*WQ+w
}

// ---- prologue: W_qkv (256x768) -> WqkvT (768x256) bf16; W_out -> WoutT bf16
__global__ void prep_weights(const float* __restrict__ Wqkv,
                             const float* __restrict__ Wout,
                             unsigned short* __restrict__ WqkvT,
                             unsigned short* __restrict__ WoutT) {
  int idx = blockIdx.x * 256 + threadIdx.x;
  if (idx < 256 * 768) {
    int k = idx / 768, n = idx - k * 768;
    WqkvT[n * 256 + k] = f2bf(Wqkv[idx]);
  }
  if (idx < 256 * 256) {
    int k = idx >> 8, n = idx & 255;
    WoutT[n * 256 + k] = f2bf(Wout[idx]);
  }
}

// one head: GEMM1 slice (40x96, 1-deep B prefetch) -> qbuf -> attention -> packed O regs
__device__ __forceinline__ void do_head(int head, const char* AO, char* qb,
                                        const unsigned short* __restrict__ WqkvT,
                                        const float* __restrict__ mask, int tile0,
                                        int lr, int lg, int lane,
                                        unsigned* oPk /*[16], static-indexed*/) {
  f32x4 acc[6][3];
  #pragma unroll
  for (int j = 0; j < 6; ++j)
    #pragma unroll
    for (int mt = 0; mt < 3; ++mt)
      acc[j][mt] = (f32x4){0.f, 0.f, 0.f, 0.f};

  const int hb = head * 32;
  const unsigned short* bp[6];
  bp[0] = WqkvT + (hb + lr) * 256 + lg * 8;
  bp[1] = WqkvT + (hb + 16 + lr) * 256 + lg * 8;
  bp[2] = WqkvT + (256 + hb + lr) * 256 + lg * 8;
  bp[3] = WqkvT + (256 + hb + 16 + lr) * 256 + lg * 8;
  bp[4] = WqkvT + (512 + hb + lr) * 256 + lg * 8;
  bp[5] = WqkvT + (512 + hb + 16 + lr) * 256 + lg * 8;

  bf16x8 bcur[6], bnxt[6];
  #pragma unroll
  for (int j = 0; j < 6; ++j) bcur[j] = *(const bf16x8*)(bp[j]);

  #pragma unroll
  for (int kt = 0; kt < 8; ++kt) {
    if (kt < 7) {
      #pragma unroll
      for (int j = 0; j < 6; ++j) bnxt[j] = *(const bf16x8*)(bp[j] + (kt + 1) * 32);
    }
    bf16x8 a0 = *(const bf16x8*)(AO + swzA(lr,      kt * 64 + lg * 16));
    bf16x8 a1 = *(const bf16x8*)(AO + swzA(16 + lr, kt * 64 + lg * 16));
    bf16x8 a2 = *(const bf16x8*)(AO + swzA(32 + lr, kt * 64 + lg * 16)); // rows 40-47 garbage, discarded
    #pragma unroll
    for (int j = 0; j < 6; ++j) {
      acc[j][0] = __builtin_amdgcn_mfma_f32_16x16x32_bf16(a0, bcur[j], acc[j][0], 0, 0, 0);
      acc[j][1] = __builtin_amdgcn_mfma_f32_16x16x32_bf16(a1, bcur[j], acc[j][1], 0, 0, 0);
      acc[j][2] = __builtin_amdgcn_mfma_f32_16x16x32_bf16(a2, bcur[j], acc[j][2], 0, 0, 0);
    }
    #pragma unroll
    for (int j = 0; j < 6; ++j) bcur[j] = bnxt[j];
  }

  // stage qkv into wave-private qbuf [40][192B] bf16 swizzled
  #pragma unroll
  for (int j = 0; j < 6; ++j)
    #pragma unroll
    for (int mt = 0; mt < 3; ++mt)
      #pragma unroll
      for (int rg = 0; rg < 4; ++rg) {
        int row = mt * 16 + lg * 4 + rg;
        if (row < ROWS)
          *(unsigned short*)(qb + swzQ(row, (j * 16 + lr) * 2)) = f2bf(acc[j][mt][rg]);
      }

  // attention: one lane per row, 40 lanes active
  if (lane < ROWS) {
    const int r = lane;
    const int t5 = (r / 5) * 5;
    const float* mrow = mask + (tile0 + r / 5) * 5;

    uint4 qa = *(const uint4*)(qb + swzQ(r, 0));
    uint4 qbv = *(const uint4*)(qb + swzQ(r, 16));
    uint4 qc = *(const uint4*)(qb + swzQ(r, 32));
    uint4 qd = *(const uint4*)(qb + swzQ(r, 48));
    f32x2 q2[16];
    q2[0]=bfpair(qa.x);  q2[1]=bfpair(qa.y);  q2[2]=bfpair(qa.z);  q2[3]=bfpair(qa.w);
    q2[4]=bfpair(qbv.x); q2[5]=bfpair(qbv.y); q2[6]=bfpair(qbv.z); q2[7]=bfpair(qbv.w);
    q2[8]=bfpair(qc.x);  q2[9]=bfpair(qc.y);  q2[10]=bfpair(qc.z); q2[11]=bfpair(qc.w);
    q2[12]=bfpair(qd.x); q2[13]=bfpair(qd.y); q2[14]=bfpair(qd.z); q2[15]=bfpair(qd.w);

    float p[5];
    #pragma unroll
    for (int j = 0; j < 5; ++j) {
      const int rk = t5 + j;
      uint4 ka = *(const uint4*)(qb + swzQ(rk, 64));
      uint4 kb = *(const uint4*)(qb + swzQ(rk, 80));
      uint4 kc = *(const uint4*)(qb + swzQ(rk, 96));
      uint4 kd = *(const uint4*)(qb + swzQ(rk, 112));
      f32x2 d2 = (f32x2){0.f, 0.f};
      d2 += q2[0]*bfpair(ka.x);  d2 += q2[1]*bfpair(ka.y);
      d2 += q2[2]*bfpair(ka.z);  d2 += q2[3]*bfpair(ka.w);
      d2 += q2[4]*bfpair(kb.x);  d2 += q2[5]*bfpair(kb.y);
      d2 += q2[6]*bfpair(kb.z);  d2 += q2[7]*bfpair(kb.w);
      d2 += q2[8]*bfpair(kc.x);  d2 += q2[9]*bfpair(kc.y);
      d2 += q2[10]*bfpair(kc.z); d2 += q2[11]*bfpair(kc.w);
      d2 += q2[12]*bfpair(kd.x); d2 += q2[13]*bfpair(kd.y);
      d2 += q2[14]*bfpair(kd.z); d2 += q2[15]*bfpair(kd.w);
      float d = (d2.x + d2.y) * SCALE_QK;
      p[j] = (mrow[j] == 0.0f) ? -1e30f : d;
    }
    float mx = fmaxf(fmaxf(fmaxf(p[0], p[1]), fmaxf(p[2], p[3])), p[4]);
    float sum = 0.f;
    #pragma unroll
    for (int j = 0; j < 5; ++j) { p[j] = __expf(p[j] - mx); sum += p[j]; }
    const float inv = 1.0f / sum;

    f32x2 o2[16];
    #pragma unroll
    for (int c = 0; c < 16; ++c) o2[c] = (f32x2){0.f, 0.f};
    #pragma unroll
    for (int j = 0; j < 5; ++j) {
      const int rv = t5 + j;
      uint4 va = *(const uint4*)(qb + swzQ(rv, 128));
      uint4 vb = *(const uint4*)(qb + swzQ(rv, 144));
      uint4 vc = *(const uint4*)(qb + swzQ(rv, 160));
      uint4 vd = *(const uint4*)(qb + swzQ(rv, 176));
      f32x2 pj2 = (f32x2){p[j], p[j]};
      o2[0]  += pj2*bfpair(va.x); o2[1]  += pj2*bfpair(va.y);
      o2[2]  += pj2*bfpair(va.z); o2[3]  += pj2*bfpair(va.w);
      o2[4]  += pj2*bfpair(vb.x); o2[5]  += pj2*bfpair(vb.y);
      o2[6]  += pj2*bfpair(vb.z); o2[7]  += pj2*bfpair(vb.w);
      o2[8]  += pj2*bfpair(vc.x); o2[9]  += pj2*bfpair(vc.y);
      o2[10] += pj2*bfpair(vc.z); o2[11] += pj2*bfpair(vc.w);
      o2[12] += pj2*bfpair(vd.x); o2[13] += pj2*bfpair(vd.y);
      o2[14] += pj2*bfpair(vd.z); o2[15] += pj2*bfpair(vd.w);
    }
    f32x2 inv2 = (f32x2){inv, inv};
    #pragma unroll
    for (int c = 0; c < 16; ++c) oPk[c] = pack2(o2[c] * inv2);
  }
}

__global__ __launch_bounds__(256, 2)
void cav_attn_fused(const float* __restrict__ x,
                    const float* __restrict__ mask,
                    const unsigned short* __restrict__ WqkvT,
                    const unsigned short* __restrict__ WoutT,
                    const float* __restrict__ b_out,
                    float* __restrict__ out) {
  extern __shared__ char smem[];
  char* AO = smem + AO_OFF;

  const int tid  = threadIdx.x;
  const int wave = tid >> 6;
  const int lane = tid & 63;
  const int lr   = lane & 15;
  const int lg   = lane >> 4;
  const int tile0 = blockIdx.x * TPB;

  // ---- P0: stage x tile -> AO (bf16, swizzled); offsets computed inline
  #pragma unroll
  for (int i = 0; i < 10; ++i) {
    int r = i * 4 + wave;
    f32x4 v = *(const f32x4*)(x + row_gofs(tile0, r) + lane * 4);
    ushort4 pk;
    pk.x = f2bf(v[0]); pk.y = f2bf(v[1]); pk.z = f2bf(v[2]); pk.w = f2bf(v[3]);
    *(ushort4*)(AO + swzA(r, lane * 8)) = pk;
  }
  __syncthreads();

  char* qb = smem + QBUF_OFF + wave * QBUF_STRIDE;
  unsigned oPk0[16], oPk1[16];
  do_head(wave * 2,     AO, qb, WqkvT, mask, tile0, lr, lg, lane, oPk0);
  do_head(wave * 2 + 1, AO, qb, WqkvT, mask, tile0, lr, lg, lane, oPk1);

  __syncthreads();   // all GEMM1 A-reads complete across waves

  // ---- write O over the A region (bf16, swizzled); wave-disjoint columns
  if (lane < ROWS) {
    const int r = lane;
    int b0 = (wave * 2) * 64;
    *(uint4*)(AO + swzA(r, b0))      = make_uint4(oPk0[0],  oPk0[1],  oPk0[2],  oPk0[3]);
    *(uint4*)(AO + swzA(r, b0 + 16)) = make_uint4(oPk0[4],  oPk0[5],  oPk0[6],  oPk0[7]);
    *(uint4*)(AO + swzA(r, b0 + 32)) = make_uint4(oPk0[8],  oPk0[9],  oPk0[10], oPk0[11]);
    *(uint4*)(AO + swzA(r, b0 + 48)) = make_uint4(oPk0[12], oPk0[13], oPk0[14], oPk0[15]);
    int b1 = (wave * 2 + 1) * 64;
    *(uint4*)(AO + swzA(r, b1))      = make_uint4(oPk1[0],  oPk1[1],  oPk1[2],  oPk1[3]);
    *(uint4*)(AO + swzA(r, b1 + 16)) = make_uint4(oPk1[4],  oPk1[5],  oPk1[6],  oPk1[7]);
    *(uint4*)(AO + swzA(r, b1 + 32)) = make_uint4(oPk1[8],  oPk1[9],  oPk1[10], oPk1[11]);
    *(uint4*)(AO + swzA(r, b1 + 48)) = make_uint4(oPk1[12], oPk1[13], oPk1[14], oPk1[15]);
  }
  __syncthreads();

  // ---- P2: out = O @ Wout + b_out; wave owns cols [wave*64, wave*64+64)
  f32x4 acc2[4][3];
  #pragma unroll
  for (int j = 0; j < 4; ++j)
    #pragma unroll
    for (int mt = 0; mt < 3; ++mt)
      acc2[j][mt] = (f32x4){0.f, 0.f, 0.f, 0.f};

  const unsigned short* bp2[4];
  #pragma unroll
  for (int j = 0; j < 4; ++j)
    bp2[j] = WoutT + (wave * 64 + j * 16 + lr) * 256 + lg * 8;

  bf16x8 bcur2[4], bnxt2[4];
  #pragma unroll
  for (int j = 0; j < 4; ++j) bcur2[j] = *(const bf16x8*)(bp2[j]);

  #pragma unroll
  for (int kt = 0; kt < 8; ++kt) {
    if (kt < 7) {
      #pragma unroll
      for (int j = 0; j < 4; ++j) bnxt2[j] = *(const bf16x8*)(bp2[j] + (kt + 1) * 32);
    }
    bf16x8 a0 = *(const bf16x8*)(AO + swzA(lr,      kt * 64 + lg * 16));
    bf16x8 a1 = *(const bf16x8*)(AO + swzA(16 + lr, kt * 64 + lg * 16));
    bf16x8 a2 = *(const bf16x8*)(AO + swzA(32 + lr, kt * 64 + lg * 16));
    #pragma unroll
    for (int j = 0; j < 4; ++j) {
      acc2[j][0] = __builtin_amdgcn_mfma_f32_16x16x32_bf16(a0, bcur2[j], acc2[j][0], 0, 0, 0);
      acc2[j][1] = __builtin_amdgcn_mfma_f32_16x16x32_bf16(a1, bcur2[j], acc2[j][1], 0, 0, 0);
      acc2[j][2] = __builtin_amdgcn_mfma_f32_16x16x32_bf16(a2, bcur2[j], acc2[j][2], 0, 0, 0);
    }
    #pragma unroll
    for (int j = 0; j < 4; ++j) bcur2[j] = bnxt2[j];
  }
  __syncthreads();   // all O reads done before f32 overlay

  // ---- epilogue: stage f32 rows in LDS [40][1024B], then coalesced 1KB-row stores
  #pragma unroll
  for (int j = 0; j < 4; ++j) {
    const int col = wave * 64 + j * 16 + lr;
    const float bo = b_out[col];
    #pragma unroll
    for (int mt = 0; mt < 3; ++mt)
      #pragma unroll
      for (int rg = 0; rg < 4; ++rg) {
        int row = mt * 16 + lg * 4 + rg;
        if (row < ROWS)
          *(float*)(smem + row * 1024 + col * 4) = acc2[j][mt][rg] + bo;
      }
  }
  __syncthreads();
  #pragma unroll
  for (int i = 0; i < 10; ++i) {
    int r = i * 4 + wave;
    f32x4 v = *(const f32x4*)(smem + r * 1024 + lane * 16);
    *(f32x4*)(out + row_gofs(tile0, r) + lane * 4) = v;
  }
}

extern "C" void kernel_launch(void* const* d_in, const int* in_sizes, int n_in,
                              void* d_out, int out_size, void* d_ws, size_t ws_size,
                              hipStream_t stream) {
  (void)in_sizes; (void)n_in; (void)out_size; (void)ws_size;
  const float* x    = (const float*)d_in[0];
  const float* mask = (const float*)d_in[1];
  const float* Wqkv = (const float*)d_in[2];
  const float* Wout = (const float*)d_in[3];
  const float* bout = (const float*)d_in[4];
  float* out = (float*)d_out;

  unsigned short* WqkvT = (unsigned short*)d_ws;        // [768][256]
  unsigned short* WoutT = WqkvT + 768 * 256;            // [256][256]

  prep_weights<<<768, 256, 0, stream>>>(Wqkv, Wout, WqkvT, WoutT);
  cav_attn_fused<<<NBLK, 256, SMEM_BYTES, stream>>>(x, mask, WqkvT, WoutT, bout, out);
}

// Round 7
// 348.207 us; speedup vs baseline: 1.3745x; 1.0985x over previous
//
#include <hip/hip_runtime.h>
#include <hip/hip_bf16.h>

// CavAttention: B=2, L=5, H=100, W=176, C=256, HEADS=8, DH=32, inner=256
#define LQ 5
#define HQ 100
#define WQ 176
#define HWQ 17600
#define NT 35200
#define TPB 8
#define ROWS 40
#define NBLK 4400
#define SCALE_QK 0.17677669529663687f

// LDS layout (bytes):
//  AO    [40][512B] bf16 swz        : 0     .. 20480   (x-tile, GEMM1 A; rows 40-47
//                                                        fragment reads spill into qbuf: garbage, discarded)
//  qbuf  4w x [40][192B] bf16 swz   : 20480 .. 51200   (q|k|v of the current head)
//  maskb [40] f32 additive bias     : 51200 .. 51360
//  gofs  [40] i32                   : 51360 .. 51520
//  OBUF  4w x 2h x [40][64B] swz    : 51520 .. 72000   (attention out; +512 pad for
//                                                        garbage reads of rows 40-47)
#define AO_OFF 0
#define QBUF_OFF 20480
#define QBUF_STRIDE 7680
#define MASK_OFF 51200
#define GOFS_OFF 51360
#define OBUF_OFF 51520
#define OBUF_WSTRIDE 5120
#define OBUF_HSTRIDE 2560
#define SMEM_BYTES 72512

typedef __attribute__((ext_vector_type(8))) short bf16x8;
typedef __attribute__((ext_vector_type(4))) float f32x4;
typedef __attribute__((ext_vector_type(2))) float f32x2;

__device__ __forceinline__ unsigned short f2bf(float f) {
  __hip_bfloat16 b = __float2bfloat16(f);
  return *(unsigned short*)&b;
}
__device__ __forceinline__ f32x2 bfpair(unsigned w) {
  union { unsigned u; float f; } lo, hi;
  lo.u = w << 16; hi.u = w & 0xffff0000u;
  return (f32x2){lo.f, hi.f};
}
__device__ __forceinline__ unsigned pack2(f32x2 v) {
  return ((unsigned)f2bf(v.y) << 16) | (unsigned)f2bf(v.x);
}
// XOR swizzles; write/read use identical maps
__device__ __forceinline__ int swzA(int row, int b) { return (row * 512 + b) ^ ((row & 7) << 4); }
__device__ __forceinline__ int swzQ(int row, int b) { return (row * 192 + b) ^ ((row & 7) << 4); }
__device__ __forceinline__ int swzO(int row, int b) { return row * 64 + (b ^ ((row & 3) << 4)); }

// packed bf16 pair dot: d += a0*b0 + a1*b1
#if __has_builtin(__builtin_amdgcn_fdot2_f32_bf16)
typedef __attribute__((ext_vector_type(2))) __bf16 bf16x2v;
__device__ __forceinline__ float dot2bf(unsigned a, unsigned b, float c) {
  union { unsigned u; bf16x2v v; } ua, ub;
  ua.u = a; ub.u = b;
  return __builtin_amdgcn_fdot2_f32_bf16(ua.v, ub.v, c, false);
}
#else
__device__ __forceinline__ float dot2bf(unsigned a, unsigned b, float c) {
  f32x2 pa = bfpair(a), pb = bfpair(b);
  return __builtin_fmaf(pa.y, pb.y, __builtin_fmaf(pa.x, pb.x, c));
}
#endif

// ---- prologue: W_qkv (256x768) -> WqkvT (768x256) bf16; W_out -> WoutT bf16
__global__ void prep_weights(const float* __restrict__ Wqkv,
                             const float* __restrict__ Wout,
                             unsigned short* __restrict__ WqkvT,
                             unsigned short* __restrict__ WoutT) {
  int idx = blockIdx.x * 256 + threadIdx.x;
  if (idx < 256 * 768) {
    int k = idx / 768, n = idx - k * 768;
    WqkvT[n * 256 + k] = f2bf(Wqkv[idx]);
  }
  if (idx < 256 * 256) {
    int k = idx >> 8, n = idx & 255;
    WoutT[n * 256 + k] = f2bf(Wout[idx]);
  }
}

// one head: GEMM1 (depth-2 B prefetch) -> qbuf -> attention -> O into LDS (ob)
__device__ __forceinline__ void do_head(int head, const char* AO, char* qb, char* ob,
                                        const unsigned short* __restrict__ WqkvT,
                                        const float* maskb,
                                        int lr, int lg, int lane) {
  f32x4 acc[6][3];
  #pragma unroll
  for (int j = 0; j < 6; ++j)
    #pragma unroll
    for (int mt = 0; mt < 3; ++mt)
      acc[j][mt] = (f32x4){0.f, 0.f, 0.f, 0.f};

  const int hb = head * 32;
  const unsigned short* bp[6];
  bp[0] = WqkvT + (hb + lr) * 256 + lg * 8;
  bp[1] = WqkvT + (hb + 16 + lr) * 256 + lg * 8;
  bp[2] = WqkvT + (256 + hb + lr) * 256 + lg * 8;
  bp[3] = WqkvT + (256 + hb + 16 + lr) * 256 + lg * 8;
  bp[4] = WqkvT + (512 + hb + lr) * 256 + lg * 8;
  bp[5] = WqkvT + (512 + hb + 16 + lr) * 256 + lg * 8;

  bf16x8 bb0[6], bb1[6];
  #pragma unroll
  for (int j = 0; j < 6; ++j) {
    bb0[j] = *(const bf16x8*)(bp[j]);
    bb1[j] = *(const bf16x8*)(bp[j] + 32);
  }

  #pragma unroll
  for (int kt = 0; kt < 8; ++kt) {
    bf16x8 a0 = *(const bf16x8*)(AO + swzA(lr,      kt * 64 + lg * 16));
    bf16x8 a1 = *(const bf16x8*)(AO + swzA(16 + lr, kt * 64 + lg * 16));
    bf16x8 a2 = *(const bf16x8*)(AO + swzA(32 + lr, kt * 64 + lg * 16)); // rows 40-47 garbage, discarded
    #pragma unroll
    for (int j = 0; j < 6; ++j) {
      bf16x8 bv = (kt & 1) ? bb1[j] : bb0[j];
      acc[j][0] = __builtin_amdgcn_mfma_f32_16x16x32_bf16(a0, bv, acc[j][0], 0, 0, 0);
      acc[j][1] = __builtin_amdgcn_mfma_f32_16x16x32_bf16(a1, bv, acc[j][1], 0, 0, 0);
      acc[j][2] = __builtin_amdgcn_mfma_f32_16x16x32_bf16(a2, bv, acc[j][2], 0, 0, 0);
    }
    if (kt < 6) {
      #pragma unroll
      for (int j = 0; j < 6; ++j) {
        bf16x8 nl = *(const bf16x8*)(bp[j] + (kt + 2) * 32);
        if (kt & 1) bb1[j] = nl; else bb0[j] = nl;
      }
    }
  }

  // stage qkv into wave-private qbuf [40][192B] bf16 swizzled
  #pragma unroll
  for (int j = 0; j < 6; ++j)
    #pragma unroll
    for (int mt = 0; mt < 3; ++mt)
      #pragma unroll
      for (int rg = 0; rg < 4; ++rg) {
        int row = mt * 16 + lg * 4 + rg;
        if (row < ROWS)
          *(unsigned short*)(qb + swzQ(row, (j * 16 + lr) * 2)) = f2bf(acc[j][mt][rg]);
      }

  // attention: one lane per row, 40 lanes active; q/k stay packed (dot2bf)
  if (lane < ROWS) {
    const int r = lane;
    const int t5 = (r / 5) * 5;
    uint4 q0 = *(const uint4*)(qb + swzQ(r, 0));
    uint4 q1 = *(const uint4*)(qb + swzQ(r, 16));
    uint4 q2 = *(const uint4*)(qb + swzQ(r, 32));
    uint4 q3 = *(const uint4*)(qb + swzQ(r, 48));

    float p[5];
    #pragma unroll
    for (int j = 0; j < 5; ++j) {
      const int rk = t5 + j;
      uint4 k0 = *(const uint4*)(qb + swzQ(rk, 64));
      uint4 k1 = *(const uint4*)(qb + swzQ(rk, 80));
      uint4 k2 = *(const uint4*)(qb + swzQ(rk, 96));
      uint4 k3 = *(const uint4*)(qb + swzQ(rk, 112));
      float d = 0.f;
      d = dot2bf(q0.x, k0.x, d); d = dot2bf(q0.y, k0.y, d);
      d = dot2bf(q0.z, k0.z, d); d = dot2bf(q0.w, k0.w, d);
      d = dot2bf(q1.x, k1.x, d); d = dot2bf(q1.y, k1.y, d);
      d = dot2bf(q1.z, k1.z, d); d = dot2bf(q1.w, k1.w, d);
      d = dot2bf(q2.x, k2.x, d); d = dot2bf(q2.y, k2.y, d);
      d = dot2bf(q2.z, k2.z, d); d = dot2bf(q2.w, k2.w, d);
      d = dot2bf(q3.x, k3.x, d); d = dot2bf(q3.y, k3.y, d);
      d = dot2bf(q3.z, k3.z, d); d = dot2bf(q3.w, k3.w, d);
      p[j] = d * SCALE_QK + maskb[rk];
    }
    float mx = fmaxf(fmaxf(fmaxf(p[0], p[1]), fmaxf(p[2], p[3])), p[4]);
    float sum = 0.f;
    #pragma unroll
    for (int j = 0; j < 5; ++j) { p[j] = __expf(p[j] - mx); sum += p[j]; }
    const float inv = 1.0f / sum;
    #pragma unroll
    for (int j = 0; j < 5; ++j) p[j] *= inv;

    f32x2 o2[16];
    #pragma unroll
    for (int c = 0; c < 16; ++c) o2[c] = (f32x2){0.f, 0.f};
    #pragma unroll
    for (int j = 0; j < 5; ++j) {
      const int rv = t5 + j;
      uint4 v0 = *(const uint4*)(qb + swzQ(rv, 128));
      uint4 v1 = *(const uint4*)(qb + swzQ(rv, 144));
      uint4 v2 = *(const uint4*)(qb + swzQ(rv, 160));
      uint4 v3 = *(const uint4*)(qb + swzQ(rv, 176));
      f32x2 pj2 = (f32x2){p[j], p[j]};
      o2[0]  += pj2 * bfpair(v0.x); o2[1]  += pj2 * bfpair(v0.y);
      o2[2]  += pj2 * bfpair(v0.z); o2[3]  += pj2 * bfpair(v0.w);
      o2[4]  += pj2 * bfpair(v1.x); o2[5]  += pj2 * bfpair(v1.y);
      o2[6]  += pj2 * bfpair(v1.z); o2[7]  += pj2 * bfpair(v1.w);
      o2[8]  += pj2 * bfpair(v2.x); o2[9]  += pj2 * bfpair(v2.y);
      o2[10] += pj2 * bfpair(v2.z); o2[11] += pj2 * bfpair(v2.w);
      o2[12] += pj2 * bfpair(v3.x); o2[13] += pj2 * bfpair(v3.y);
      o2[14] += pj2 * bfpair(v3.z); o2[15] += pj2 * bfpair(v3.w);
    }
    unsigned oPk[16];
    #pragma unroll
    for (int c = 0; c < 16; ++c) oPk[c] = pack2(o2[c]);
    const int sx = (r & 3) << 4;
    *(uint4*)(ob + r * 64 + (0 ^ sx))  = make_uint4(oPk[0],  oPk[1],  oPk[2],  oPk[3]);
    *(uint4*)(ob + r * 64 + (16 ^ sx)) = make_uint4(oPk[4],  oPk[5],  oPk[6],  oPk[7]);
    *(uint4*)(ob + r * 64 + (32 ^ sx)) = make_uint4(oPk[8],  oPk[9],  oPk[10], oPk[11]);
    *(uint4*)(ob + r * 64 + (48 ^ sx)) = make_uint4(oPk[12], oPk[13], oPk[14], oPk[15]);
  }
}

__global__ __launch_bounds__(256, 2)
void cav_attn_fused(const float* __restrict__ x,
                    const float* __restrict__ mask,
                    const unsigned short* __restrict__ WqkvT,
                    const unsigned short* __restrict__ WoutT,
                    const float* __restrict__ b_out,
                    float* __restrict__ out) {
  extern __shared__ char smem[];
  char*  AO    = smem + AO_OFF;
  float* maskb = (float*)(smem + MASK_OFF);
  int*   gofs  = (int*)(smem + GOFS_OFF);

  const int tid  = threadIdx.x;
  const int wave = tid >> 6;
  const int lane = tid & 63;
  const int lr   = lane & 15;
  const int lg   = lane >> 4;
  const int tile0 = blockIdx.x * TPB;

  // per-row tables; every wave writes identical values -> same-wave reads, no barrier
  if (lane < ROWS) {
    int tt = lane / LQ;
    int l  = lane - tt * LQ;
    int gt = tile0 + tt;
    int b  = (gt >= HWQ) ? 1 : 0;
    int rem = gt - b * HWQ;                       // h*WQ + w
    gofs[lane] = (((b * LQ + l) * HQ) * WQ + rem) << 8;
    float mv = mask[gt * LQ + l];
    maskb[lane] = (mv == 0.0f) ? -1e30f : 0.0f;
  }

  // ---- P0: stage x tile -> AO (bf16, swizzled)
  #pragma unroll
  for (int i = 0; i < 10; ++i) {
    int r = i * 4 + wave;
    f32x4 v = *(const f32x4*)(x + gofs[r] + lane * 4);
    ushort4 pk;
    pk.x = f2bf(v[0]); pk.y = f2bf(v[1]); pk.z = f2bf(v[2]); pk.w = f2bf(v[3]);
    *(ushort4*)(AO + swzA(r, lane * 8)) = pk;
  }
  __syncthreads();

  char* qb = smem + QBUF_OFF + wave * QBUF_STRIDE;
  char* ob = smem + OBUF_OFF + wave * OBUF_WSTRIDE;
  do_head(wave * 2,     AO, qb, ob,                WqkvT, maskb, lr, lg, lane);
  do_head(wave * 2 + 1, AO, qb, ob + OBUF_HSTRIDE, WqkvT, maskb, lr, lg, lane);
  __syncthreads();   // all O tiles visible to all waves

  // ---- P2: out = O @ Wout + b_out; wave owns cols [wave*64, wave*64+64)
  f32x4 acc2[4][3];
  #pragma unroll
  for (int j = 0; j < 4; ++j)
    #pragma unroll
    for (int mt = 0; mt < 3; ++mt)
      acc2[j][mt] = (f32x4){0.f, 0.f, 0.f, 0.f};

  const unsigned short* bp2[4];
  #pragma unroll
  for (int j = 0; j < 4; ++j)
    bp2[j] = WoutT + (wave * 64 + j * 16 + lr) * 256 + lg * 8;

  bf16x8 cc0[4], cc1[4];
  #pragma unroll
  for (int j = 0; j < 4; ++j) {
    cc0[j] = *(const bf16x8*)(bp2[j]);
    cc1[j] = *(const bf16x8*)(bp2[j] + 32);
  }

  #pragma unroll
  for (int kt = 0; kt < 8; ++kt) {
    // O cols [kt*32, kt*32+32) = head kt -> wave kt>>1, head-slot kt&1
    const char* OB = smem + OBUF_OFF + (kt >> 1) * OBUF_WSTRIDE + (kt & 1) * OBUF_HSTRIDE;
    bf16x8 a0 = *(const bf16x8*)(OB + swzO(lr,      lg * 16));
    bf16x8 a1 = *(const bf16x8*)(OB + swzO(16 + lr, lg * 16));
    bf16x8 a2 = *(const bf16x8*)(OB + swzO(32 + lr, lg * 16)); // rows 40-47 garbage (padded), discarded
    #pragma unroll
    for (int j = 0; j < 4; ++j) {
      bf16x8 bv = (kt & 1) ? cc1[j] : cc0[j];
      acc2[j][0] = __builtin_amdgcn_mfma_f32_16x16x32_bf16(a0, bv, acc2[j][0], 0, 0, 0);
      acc2[j][1] = __builtin_amdgcn_mfma_f32_16x16x32_bf16(a1, bv, acc2[j][1], 0, 0, 0);
      acc2[j][2] = __builtin_amdgcn_mfma_f32_16x16x32_bf16(a2, bv, acc2[j][2], 0, 0, 0);
    }
    if (kt < 6) {
      #pragma unroll
      for (int j = 0; j < 4; ++j) {
        bf16x8 nl = *(const bf16x8*)(bp2[j] + (kt + 2) * 32);
        if (kt & 1) cc1[j] = nl; else cc0[j] = nl;
      }
    }
  }

  // ---- direct global stores (64B per 16-lane group)
  #pragma unroll
  for (int j = 0; j < 4; ++j) {
    const int col = wave * 64 + j * 16 + lr;
    const float bo = b_out[col];
    #pragma unroll
    for (int mt = 0; mt < 3; ++mt)
      #pragma unroll
      for (int rg = 0; rg < 4; ++rg) {
        int row = mt * 16 + lg * 4 + rg;
        if (row < ROWS)
          out[gofs[row] + col] = acc2[j][mt][rg] + bo;
      }
  }
}

extern "C" void kernel_launch(void* const* d_in, const int* in_sizes, int n_in,
                              void* d_out, int out_size, void* d_ws, size_t ws_size,
                              hipStream_t stream) {
  (void)in_sizes; (void)n_in; (void)out_size; (void)ws_size;
  const float* x    = (const float*)d_in[0];
  const float* mask = (const float*)d_in[1];
  const float* Wqkv = (const float*)d_in[2];
  const float* Wout = (const float*)d_in[3];
  const float* bout = (const float*)d_in[4];
  float* out = (float*)d_out;

  unsigned short* WqkvT = (unsigned short*)d_ws;        // [768][256]
  unsigned short* WoutT = WqkvT + 768 * 256;            // [256][256]

  (void)hipFuncSetAttribute((const void*)cav_attn_fused,
                            hipFuncAttributeMaxDynamicSharedMemorySize, SMEM_BYTES);

  prep_weights<<<768, 256, 0, stream>>>(Wqkv, Wout, WqkvT, WoutT);
  cav_attn_fused<<<NBLK, 256, SMEM_BYTES, stream>>>(x, mask, WqkvT, WoutT, bout, out);
}